// Round 5
// baseline (1086.323 us; speedup 1.0000x reference)
//
#include <hip/hip_runtime.h>
#include <stdint.h>

#define N_NODES 50000
#define DIM_MEM 512
#define DIM_MSG 1280
#define N_MSG   100000

typedef __attribute__((ext_vector_type(8))) short bf16x8;
typedef __attribute__((ext_vector_type(4))) float f32x4;

template <int N> struct ic { static constexpr int v = N; };

__device__ __forceinline__ unsigned short f2bf(float f) {
  union { float f; uint32_t u; } v; v.f = f;
  uint32_t u = v.u;
  u += 0x7fffu + ((u >> 16) & 1u);   // round-to-nearest-even
  return (unsigned short)(u >> 16);
}

// ---------------- kernel 1: segment mean (seg_ids sorted) ----------------
__global__ __launch_bounds__(64) void k_segmean(
    const float* __restrict__ msg, const int* __restrict__ seg,
    unsigned short* __restrict__ means, int* __restrict__ counts)
{
  int node = blockIdx.x;
  int lane = threadIdx.x;

  int lo = 0, hi = N_MSG;
  while (lo < hi) { int m = (lo + hi) >> 1; if (seg[m] < node) lo = m + 1; else hi = m; }
  int start = lo;
  hi = N_MSG;
  while (lo < hi) { int m = (lo + hi) >> 1; if (seg[m] < node + 1) lo = m + 1; else hi = m; }
  int end = lo;
  int cnt = end - start;
  if (lane == 0) counts[node] = cnt;

  float4 s[5];
#pragma unroll
  for (int j = 0; j < 5; j++) s[j] = make_float4(0.f, 0.f, 0.f, 0.f);
  const float4* m4 = (const float4*)msg;   // 320 float4 per row
  for (int r = start; r < end; r++) {
#pragma unroll
    for (int j = 0; j < 5; j++) {
      float4 v = m4[r * 320 + j * 64 + lane];
      s[j].x += v.x; s[j].y += v.y; s[j].z += v.z; s[j].w += v.w;
    }
  }
  float inv = (cnt > 0) ? 1.0f / (float)cnt : 0.0f;
  ushort4* o4 = (ushort4*)means;
#pragma unroll
  for (int j = 0; j < 5; j++) {
    ushort4 o;
    o.x = f2bf(s[j].x * inv); o.y = f2bf(s[j].y * inv);
    o.z = f2bf(s[j].z * inv); o.w = f2bf(s[j].w * inv);
    o4[node * 320 + j * 64 + lane] = o;
  }
}

// ---------------- kernel 2: f32 -> bf16 cast ----------------
__global__ __launch_bounds__(256) void k_cvt(
    const float* __restrict__ in, unsigned short* __restrict__ out, int n4)
{
  int i = blockIdx.x * 256 + threadIdx.x;
  if (i >= n4) return;
  float4 v = ((const float4*)in)[i];
  ushort4 o;
  o.x = f2bf(v.x); o.y = f2bf(v.y); o.z = f2bf(v.z); o.w = f2bf(v.w);
  ((ushort4*)out)[i] = o;
}

// ---------------- kernel 3: fused GEMM (6 strips) + GRU epilogue ----------------
// m97-proportioned: 256 threads (4 waves), tile 64 rows x 64 cols, wave = 64r x 16c.
// Single-buffered LDS (32 KB), plain 2-barrier loop; pipelining comes from
// 3 blocks/CU TLP (launch_bounds(256,3) caps regs at 170).
// 28 K-chunks: 0..19 = means@W_ih^T (K=1280), 20..27 = memb@W_hh^T (K=512).
__global__ __launch_bounds__(256, 3) void k_gru(
    const unsigned short* __restrict__ means, const unsigned short* __restrict__ memb,
    const unsigned short* __restrict__ wih,   const unsigned short* __restrict__ whh,
    const float* __restrict__ b_ih, const float* __restrict__ b_hh,
    const float* __restrict__ memory, const int* __restrict__ counts,
    float* __restrict__ out)
{
  // A: 512 slots of 16B, slot = kc*64 + row       (kc 0..7, row 0..63)   8 KB
  // B: 1536 slots of 16B, slot = st*512 + kc*64 + col (st 0..2, col 0..63) 24 KB
  __shared__ unsigned short Al[512 * 8];
  __shared__ unsigned short Bl[1536 * 8];

  int tid = threadIdx.x;
  int lane = tid & 63, wid = tid >> 2 >> 4;   // wid = tid>>6: 4 waves
  int wc = wid;                                // col-group 0..3
  int row0 = blockIdx.y * 64;
  int c0 = blockIdx.x * 64;

  f32x4 acc[4][6];
#pragma unroll
  for (int f = 0; f < 4; f++)
#pragma unroll
    for (int s = 0; s < 6; s++) acc[f][s] = (f32x4)(0.f);

  // stage chunk c (8 global_load_lds per wave)
  auto stage = [&](int c) {
    const unsigned short* Ag; const unsigned short* Bg; int ld, k0;
    if (c < 20) { Ag = means; Bg = wih; ld = DIM_MSG; k0 = c * 64; }
    else        { Ag = memb;  Bg = whh; ld = DIM_MEM; k0 = (c - 20) * 64; }
#pragma unroll
    for (int i = 0; i < 2; i++) {
      int s = wid * 128 + i * 64 + lane;
      int row = s & 63, kc = s >> 6;
      int grow = row0 + row; if (grow > N_NODES - 1) grow = N_NODES - 1;
      const unsigned short* src = Ag + (size_t)grow * ld + k0 + kc * 8;
      __builtin_amdgcn_global_load_lds(
          (const __attribute__((address_space(1))) void*)src,
          (__attribute__((address_space(3))) void*)&Al[(wid * 128 + i * 64) * 8],
          16, 0, 0);
    }
#pragma unroll
    for (int i = 0; i < 6; i++) {
      int s = wid * 384 + i * 64 + lane;
      int st = s >> 9, r9 = s & 511;
      int kc = r9 >> 6, col = r9 & 63;
      const unsigned short* src = Bg + (size_t)(st * 512 + c0 + col) * ld + k0 + kc * 8;
      __builtin_amdgcn_global_load_lds(
          (const __attribute__((address_space(1))) void*)src,
          (__attribute__((address_space(3))) void*)&Bl[(wid * 384 + i * 64) * 8],
          16, 0, 0);
    }
  };

  // compute current chunk; SO = acc strip offset (compile-time)
  auto compute = [&](auto SO) {
    constexpr int so = decltype(SO)::v;
    int g = lane >> 4, r = lane & 15;
#pragma unroll
    for (int t = 0; t < 2; t++) {
      bf16x8 a[4], b[3];
#pragma unroll
      for (int f = 0; f < 4; f++) {
        int slot = (t * 4 + g) * 64 + (f * 16 + r);
        a[f] = *(const bf16x8*)&Al[slot * 8];
      }
#pragma unroll
      for (int st = 0; st < 3; st++) {
        int slot = st * 512 + (t * 4 + g) * 64 + (wc * 16 + r);
        b[st] = *(const bf16x8*)&Bl[slot * 8];
      }
#pragma unroll
      for (int f = 0; f < 4; f++)
#pragma unroll
        for (int st = 0; st < 3; st++)
          acc[f][so + st] = __builtin_amdgcn_mfma_f32_16x16x32_bf16(
              a[f], b[st], acc[f][so + st], 0, 0, 0);
    }
  };

  for (int c = 0; c < 20; ++c) {      // phase 1: i_r, i_z, i_n
    stage(c);
    __syncthreads();
    compute(ic<0>{});
    __syncthreads();
  }
  for (int c = 20; c < 28; ++c) {     // phase 2: h_r, h_z, h_n
    stage(c);
    __syncthreads();
    compute(ic<3>{});
    __syncthreads();
  }

  // ---- GRU epilogue ----
  int c = c0 + wc * 16 + (lane & 15);
  float bir = b_ih[c], biz = b_ih[512 + c], bin = b_ih[1024 + c];
  float bhr = b_hh[c], bhz = b_hh[512 + c], bhn = b_hh[1024 + c];
  int g = lane >> 4;
#pragma unroll
  for (int f = 0; f < 4; f++) {
    int rbase = row0 + f * 16 + g * 4;
#pragma unroll
    for (int rr = 0; rr < 4; rr++) {
      int row = rbase + rr;
      if (row < N_NODES) {
        float ir = acc[f][0][rr] + bir, iz = acc[f][1][rr] + biz, inn = acc[f][2][rr] + bin;
        float hr = acc[f][3][rr] + bhr, hz = acc[f][4][rr] + bhz, hn = acc[f][5][rr] + bhn;
        float rg = 1.f / (1.f + __expf(-(ir + hr)));
        float zg = 1.f / (1.f + __expf(-(iz + hz)));
        float cd = tanhf(inn + rg * hn);
        float h = memory[(size_t)row * DIM_MEM + c];
        float o = (counts[row] > 0) ? (1.f - zg) * cd + zg * h : h;
        out[(size_t)row * DIM_MEM + c] = o;
      }
    }
  }
}

// ---------------- launch ----------------
extern "C" void kernel_launch(void* const* d_in, const int* in_sizes, int n_in,
                              void* d_out, int out_size, void* d_ws, size_t ws_size,
                              hipStream_t stream) {
  const float* msg  = (const float*)d_in[0];
  const int*   seg  = (const int*)d_in[1];
  const float* mem  = (const float*)d_in[2];
  const float* W_ih = (const float*)d_in[3];
  const float* W_hh = (const float*)d_in[4];
  const float* b_ih = (const float*)d_in[5];
  const float* b_hh = (const float*)d_in[6];
  float* out = (float*)d_out;

  char* ws = (char*)d_ws;
  unsigned short* means = (unsigned short*)(ws);                     // 128,000,000 B
  unsigned short* memb  = (unsigned short*)(ws + 128000000LL);       //  51,200,000 B
  unsigned short* wihb  = (unsigned short*)(ws + 179200000LL);       //   3,932,160 B
  unsigned short* whhb  = (unsigned short*)(ws + 183132160LL);       //   1,572,864 B
  int* counts           = (int*)(ws + 184705024LL);                  //     200,000 B

  k_segmean<<<N_NODES, 64, 0, stream>>>(msg, seg, means, counts);
  k_cvt<<<(N_NODES * DIM_MEM / 4 + 255) / 256, 256, 0, stream>>>(mem, memb, N_NODES * DIM_MEM / 4);
  k_cvt<<<(3 * DIM_MEM * DIM_MSG / 4 + 255) / 256, 256, 0, stream>>>(W_ih, wihb, 3 * DIM_MEM * DIM_MSG / 4);
  k_cvt<<<(3 * DIM_MEM * DIM_MEM / 4 + 255) / 256, 256, 0, stream>>>(W_hh, whhb, 3 * DIM_MEM * DIM_MEM / 4);

  dim3 grid(8, (N_NODES + 63) / 64, 1);   // blockIdx.x = col-tile (L2/XCD-aligned)
  k_gru<<<grid, 256, 0, stream>>>(means, memb, wihb, whhb, b_ih, b_hh, mem, counts, out);
}

// Round 6
// 780.193 us; speedup vs baseline: 1.3924x; 1.3924x over previous
//
#include <hip/hip_runtime.h>
#include <stdint.h>

#define N_NODES 50000
#define DIM_MEM 512
#define DIM_MSG 1280
#define N_MSG   100000

typedef __attribute__((ext_vector_type(8))) short bf16x8;
typedef __attribute__((ext_vector_type(4))) float f32x4;

template <int N> struct ic { static constexpr int v = N; };

// counted vmcnt wait + scheduler fence (rule #18)
#define WAITV(n) do { asm volatile("s_waitcnt vmcnt(" #n ")" ::: "memory"); \
                      __builtin_amdgcn_sched_barrier(0); } while (0)
#define WAITL0() do { asm volatile("s_waitcnt lgkmcnt(0)" ::: "memory"); \
                      __builtin_amdgcn_sched_barrier(0); } while (0)

__device__ __forceinline__ unsigned short f2bf(float f) {
  union { float f; uint32_t u; } v; v.f = f;
  uint32_t u = v.u;
  u += 0x7fffu + ((u >> 16) & 1u);   // round-to-nearest-even
  return (unsigned short)(u >> 16);
}

// ---------------- kernel 1: segment mean (seg_ids sorted) ----------------
__global__ __launch_bounds__(64) void k_segmean(
    const float* __restrict__ msg, const int* __restrict__ seg,
    unsigned short* __restrict__ means, int* __restrict__ counts)
{
  int node = blockIdx.x;
  int lane = threadIdx.x;

  int lo = 0, hi = N_MSG;
  while (lo < hi) { int m = (lo + hi) >> 1; if (seg[m] < node) lo = m + 1; else hi = m; }
  int start = lo;
  hi = N_MSG;
  while (lo < hi) { int m = (lo + hi) >> 1; if (seg[m] < node + 1) lo = m + 1; else hi = m; }
  int end = lo;
  int cnt = end - start;
  if (lane == 0) counts[node] = cnt;

  float4 s[5];
#pragma unroll
  for (int j = 0; j < 5; j++) s[j] = make_float4(0.f, 0.f, 0.f, 0.f);
  const float4* m4 = (const float4*)msg;   // 320 float4 per row
  for (int r = start; r < end; r++) {
#pragma unroll
    for (int j = 0; j < 5; j++) {
      float4 v = m4[r * 320 + j * 64 + lane];
      s[j].x += v.x; s[j].y += v.y; s[j].z += v.z; s[j].w += v.w;
    }
  }
  float inv = (cnt > 0) ? 1.0f / (float)cnt : 0.0f;
  ushort4* o4 = (ushort4*)means;
#pragma unroll
  for (int j = 0; j < 5; j++) {
    ushort4 o;
    o.x = f2bf(s[j].x * inv); o.y = f2bf(s[j].y * inv);
    o.z = f2bf(s[j].z * inv); o.w = f2bf(s[j].w * inv);
    o4[node * 320 + j * 64 + lane] = o;
  }
}

// ---------------- kernel 2: f32 -> bf16 cast ----------------
__global__ __launch_bounds__(256) void k_cvt(
    const float* __restrict__ in, unsigned short* __restrict__ out, int n4)
{
  int i = blockIdx.x * 256 + threadIdx.x;
  if (i >= n4) return;
  float4 v = ((const float4*)in)[i];
  ushort4 o;
  o.x = f2bf(v.x); o.y = f2bf(v.y); o.z = f2bf(v.z); o.w = f2bf(v.w);
  ((ushort4*)out)[i] = o;
}

// ---------------- kernel 3: fused GEMM (6 strips) + GRU epilogue ----------------
// Row-major LDS tiles [row][64k] with T2 XOR swizzle (c16 ^= row&7):
//  - staging source is lane-contiguous within each 128B row-segment (perfectly
//    coalesced, 8 fully-used lines per wave-load; was 64 lines with k-major),
//    swizzle applied by permuting the k-granule on the SOURCE (rule #21)
//  - fragment ds_read_b128 swizzled -> worst 2-way bank conflict (free, m136)
// Pipeline: 3-buffer LDS ring, counted vmcnt (5 loads/wave/chunk; vmcnt(10)
// == "chunk c landed, 2 chunks still flying").
// 28 K-chunks: 0..19 = means@W_ih^T (K=1280), 20..27 = memb@W_hh^T (K=512).
__global__ __launch_bounds__(512) void k_gru(
    const unsigned short* __restrict__ means, const unsigned short* __restrict__ memb,
    const unsigned short* __restrict__ wih,   const unsigned short* __restrict__ whh,
    const float* __restrict__ b_ih, const float* __restrict__ b_hh,
    const float* __restrict__ memory, const int* __restrict__ counts,
    float* __restrict__ out)
{
  // A: slot16 = row*8 + c16  (row 0..127, c16 0..7), content A[row][k0 + (c16^(row&7))*8]
  // B: slot16 = gcol*8 + c16 (gcol 0..191),          content W[grow][k0 + (c16^(gcol&7))*8]
  __shared__ unsigned short Al[3][128 * 64];   // 3 x 16 KB
  __shared__ unsigned short Bl[3][192 * 64];   // 3 x 24 KB   (120 KB)

  int tid = threadIdx.x;
  int lane = tid & 63, wid = tid >> 6;
  int wr = wid >> 2, wc = wid & 3;          // wave: 64 rows x 16 cols
  int row0 = blockIdx.y * 128;
  int c0 = blockIdx.x * 64;

  f32x4 acc[4][6];
#pragma unroll
  for (int f = 0; f < 4; f++)
#pragma unroll
    for (int s = 0; s < 6; s++) acc[f][s] = (f32x4)(0.f);

  int lrow = lane >> 3;                      // 0..7 : row-within-8 handled by this lane
  int csrc = (lane & 7) ^ lrow;              // inverse-swizzled source k-granule

  // stage chunk c into LDS ring buffer pb (5 global_load_lds per wave)
  auto stage = [&](int c, int pb) {
    const unsigned short* Ag; const unsigned short* Bg; int ld, k0;
    if (c < 20) { Ag = means; Bg = wih; ld = DIM_MSG; k0 = c * 64; }
    else        { Ag = memb;  Bg = whh; ld = DIM_MEM; k0 = (c - 20) * 64; }
#pragma unroll
    for (int i = 0; i < 2; i++) {            // A: 2 loads/wave, 8 rows each
      int rbase = (wid * 2 + i) * 8;         // row = rbase + lrow
      int grow = row0 + rbase + lrow; if (grow > N_NODES - 1) grow = N_NODES - 1;
      const unsigned short* src = Ag + (size_t)grow * ld + k0 + csrc * 8;
      __builtin_amdgcn_global_load_lds(
          (const __attribute__((address_space(1))) void*)src,
          (__attribute__((address_space(3))) void*)&Al[pb][rbase * 64],
          16, 0, 0);
    }
#pragma unroll
    for (int i = 0; i < 3; i++) {            // B: 3 loads/wave, 8 gate-cols each
      int gbase = (wid * 3 + i) * 8;
      int gcol = gbase + lrow;               // 0..191
      int st = gcol >> 6, col = gcol & 63;
      const unsigned short* src = Bg + (size_t)(st * 512 + c0 + col) * ld + k0 + csrc * 8;
      __builtin_amdgcn_global_load_lds(
          (const __attribute__((address_space(1))) void*)src,
          (__attribute__((address_space(3))) void*)&Bl[pb][gbase * 64],
          16, 0, 0);
    }
  };

  // compute chunk from ring buffer pb; SO = acc strip offset (compile-time)
  auto compute = [&](int pb, auto SO) {
    constexpr int so = decltype(SO)::v;
    int g = lane >> 4, r = lane & 15;
#pragma unroll
    for (int t = 0; t < 2; t++) {
      int c16 = t * 4 + g;
      bf16x8 a[4], b[3];
#pragma unroll
      for (int f = 0; f < 4; f++) {
        int row = wr * 64 + f * 16 + r;
        a[f] = *(const bf16x8*)&Al[pb][(row * 8 + (c16 ^ (r & 7))) * 8];
      }
#pragma unroll
      for (int st = 0; st < 3; st++) {
        int gcol = st * 64 + wc * 16 + r;
        b[st] = *(const bf16x8*)&Bl[pb][(gcol * 8 + (c16 ^ (r & 7))) * 8];
      }
      __builtin_amdgcn_s_setprio(1);
#pragma unroll
      for (int f = 0; f < 4; f++)
#pragma unroll
        for (int st = 0; st < 3; st++)
          acc[f][so + st] = __builtin_amdgcn_mfma_f32_16x16x32_bf16(
              a[f], b[st], acc[f][so + st], 0, 0, 0);
      __builtin_amdgcn_s_setprio(0);
    }
  };

  // prologue: 2 chunks in flight
  stage(0, 0);
  stage(1, 1);
  for (int c = 0; c < 20; ++c) {             // phase 1: i_r, i_z, i_n
    stage(c + 2, (c + 2) % 3);
    WAITV(10);                               // chunk c landed; 10 still in flight
    __builtin_amdgcn_s_barrier();
    compute(c % 3, ic<0>{});
    WAITL0();
    __builtin_amdgcn_s_barrier();            // WAR: ring slot c%3 free for c+3
  }
  for (int c = 20; c < 28; ++c) {            // phase 2: h_r, h_z, h_n
    if (c <= 25)      { stage(c + 2, (c + 2) % 3); WAITV(10); }
    else if (c == 26) { WAITV(5); }
    else              { WAITV(0); }
    __builtin_amdgcn_s_barrier();
    compute(c % 3, ic<3>{});
    WAITL0();
    __builtin_amdgcn_s_barrier();
  }

  // ---- GRU epilogue ----
  int c = c0 + wc * 16 + (lane & 15);
  float bir = b_ih[c], biz = b_ih[512 + c], bin = b_ih[1024 + c];
  float bhr = b_hh[c], bhz = b_hh[512 + c], bhn = b_hh[1024 + c];
  int g = lane >> 4;
#pragma unroll
  for (int f = 0; f < 4; f++) {
    int rbase = row0 + wr * 64 + f * 16 + g * 4;
#pragma unroll
    for (int rr = 0; rr < 4; rr++) {
      int row = rbase + rr;
      if (row < N_NODES) {
        float ir = acc[f][0][rr] + bir, iz = acc[f][1][rr] + biz, inn = acc[f][2][rr] + bin;
        float hr = acc[f][3][rr] + bhr, hz = acc[f][4][rr] + bhz, hn = acc[f][5][rr] + bhn;
        float rg = 1.f / (1.f + __expf(-(ir + hr)));
        float zg = 1.f / (1.f + __expf(-(iz + hz)));
        float cd = tanhf(inn + rg * hn);
        float h = memory[(size_t)row * DIM_MEM + c];
        float o = (counts[row] > 0) ? (1.f - zg) * cd + zg * h : h;
        out[(size_t)row * DIM_MEM + c] = o;
      }
    }
  }
}

// ---------------- launch ----------------
extern "C" void kernel_launch(void* const* d_in, const int* in_sizes, int n_in,
                              void* d_out, int out_size, void* d_ws, size_t ws_size,
                              hipStream_t stream) {
  const float* msg  = (const float*)d_in[0];
  const int*   seg  = (const int*)d_in[1];
  const float* mem  = (const float*)d_in[2];
  const float* W_ih = (const float*)d_in[3];
  const float* W_hh = (const float*)d_in[4];
  const float* b_ih = (const float*)d_in[5];
  const float* b_hh = (const float*)d_in[6];
  float* out = (float*)d_out;

  char* ws = (char*)d_ws;
  unsigned short* means = (unsigned short*)(ws);                     // 128,000,000 B
  unsigned short* memb  = (unsigned short*)(ws + 128000000LL);       //  51,200,000 B
  unsigned short* wihb  = (unsigned short*)(ws + 179200000LL);       //   3,932,160 B
  unsigned short* whhb  = (unsigned short*)(ws + 183132160LL);       //   1,572,864 B
  int* counts           = (int*)(ws + 184705024LL);                  //     200,000 B

  k_segmean<<<N_NODES, 64, 0, stream>>>(msg, seg, means, counts);
  k_cvt<<<(N_NODES * DIM_MEM / 4 + 255) / 256, 256, 0, stream>>>(mem, memb, N_NODES * DIM_MEM / 4);
  k_cvt<<<(3 * DIM_MEM * DIM_MSG / 4 + 255) / 256, 256, 0, stream>>>(W_ih, wihb, 3 * DIM_MEM * DIM_MSG / 4);
  k_cvt<<<(3 * DIM_MEM * DIM_MEM / 4 + 255) / 256, 256, 0, stream>>>(W_hh, whhb, 3 * DIM_MEM * DIM_MEM / 4);

  dim3 grid(8, (N_NODES + 127) / 128, 1);   // blockIdx.x = col-tile (L2/XCD-aligned)
  k_gru<<<grid, 512, 0, stream>>>(means, memb, wihb, whhb, b_ih, b_hh, mem, counts, out);
}

// Round 7
// 545.495 us; speedup vs baseline: 1.9914x; 1.4302x over previous
//
#include <hip/hip_runtime.h>
#include <stdint.h>

#define N_NODES 50000
#define DIM_MEM 512
#define DIM_MSG 1280
#define N_MSG   100000

typedef __attribute__((ext_vector_type(8))) short bf16x8;
typedef __attribute__((ext_vector_type(4))) float f32x4;

template <int N> struct ic { static constexpr int v = N; };

__device__ __forceinline__ unsigned short f2bf(float f) {
  union { float f; uint32_t u; } v; v.f = f;
  uint32_t u = v.u;
  u += 0x7fffu + ((u >> 16) & 1u);   // round-to-nearest-even
  return (unsigned short)(u >> 16);
}

// ---------------- kernel 1: segment mean (seg_ids sorted) ----------------
__global__ __launch_bounds__(64) void k_segmean(
    const float* __restrict__ msg, const int* __restrict__ seg,
    unsigned short* __restrict__ means, int* __restrict__ counts)
{
  int node = blockIdx.x;
  int lane = threadIdx.x;

  int lo = 0, hi = N_MSG;
  while (lo < hi) { int m = (lo + hi) >> 1; if (seg[m] < node) lo = m + 1; else hi = m; }
  int start = lo;
  hi = N_MSG;
  while (lo < hi) { int m = (lo + hi) >> 1; if (seg[m] < node + 1) lo = m + 1; else hi = m; }
  int end = lo;
  int cnt = end - start;
  if (lane == 0) counts[node] = cnt;

  float4 s[5];
#pragma unroll
  for (int j = 0; j < 5; j++) s[j] = make_float4(0.f, 0.f, 0.f, 0.f);
  const float4* m4 = (const float4*)msg;   // 320 float4 per row
  for (int r = start; r < end; r++) {
#pragma unroll
    for (int j = 0; j < 5; j++) {
      float4 v = m4[r * 320 + j * 64 + lane];
      s[j].x += v.x; s[j].y += v.y; s[j].z += v.z; s[j].w += v.w;
    }
  }
  float inv = (cnt > 0) ? 1.0f / (float)cnt : 0.0f;
  ushort4* o4 = (ushort4*)means;
#pragma unroll
  for (int j = 0; j < 5; j++) {
    ushort4 o;
    o.x = f2bf(s[j].x * inv); o.y = f2bf(s[j].y * inv);
    o.z = f2bf(s[j].z * inv); o.w = f2bf(s[j].w * inv);
    o4[node * 320 + j * 64 + lane] = o;
  }
}

// ---------------- kernel 2: f32 -> bf16 cast ----------------
__global__ __launch_bounds__(256) void k_cvt(
    const float* __restrict__ in, unsigned short* __restrict__ out, int n4)
{
  int i = blockIdx.x * 256 + threadIdx.x;
  if (i >= n4) return;
  float4 v = ((const float4*)in)[i];
  ushort4 o;
  o.x = f2bf(v.x); o.y = f2bf(v.y); o.z = f2bf(v.z); o.w = f2bf(v.w);
  ((ushort4*)out)[i] = o;
}

// ---------------- kernel 3: fused GEMM (4 strips) + GRU epilogue ----------------
// Algebraic strip reduction: GRU needs only {i_r+h_r, i_z+h_z, i_n, h_n} ->
// 4 persistent accumulators (64 f32/lane). r/z strips accumulate ACROSS both
// GEMM phases; n-strip split per phase.
// Geometry (m97 proportions): 256 threads / 4 waves; tile 64 rows x 64 cols;
// wave = 64r x 16c -> no B duplication across waves, A read 4x from LDS.
// Single-buffered 32 KB LDS, plain 2-barrier loop; pipelining via 3 blocks/CU
// (launch_bounds(256,3): acc 64 + ~80 arch regs ~= 144 < 170).
// LDS layout (R6-proven): row-major [row][64k] + XOR swizzle c16^=(row&7);
// staging source permutes k-granule (csrc = (lane&7)^lrow) -> fully coalesced.
// 28 K-chunks: 0..19 = means@W_ih^T (K=1280), 20..27 = memb@W_hh^T (K=512).
__global__ __launch_bounds__(256, 3) void k_gru(
    const unsigned short* __restrict__ means, const unsigned short* __restrict__ memb,
    const unsigned short* __restrict__ wih,   const unsigned short* __restrict__ whh,
    const float* __restrict__ b_ih, const float* __restrict__ b_hh,
    const float* __restrict__ memory, const int* __restrict__ counts,
    float* __restrict__ out)
{
  // A: slot16 = row*8 + (c16 ^ (row&7))  (row 0..63)    8 KB
  // B: slot16 = gcol*8 + (c16 ^ (gcol&7)) (gcol 0..191) 24 KB
  __shared__ unsigned short Al[64 * 64];
  __shared__ unsigned short Bl[192 * 64];

  int tid = threadIdx.x;
  int lane = tid & 63, wid = tid >> 6;       // 4 waves
  int wc = wid;                               // col-group 0..3
  int row0 = blockIdx.y * 64;
  int c0 = blockIdx.x * 64;

  f32x4 acc[4][4];                            // [row-frag][strip]: r, z, i_n, h_n
#pragma unroll
  for (int f = 0; f < 4; f++)
#pragma unroll
    for (int s = 0; s < 4; s++) acc[f][s] = (f32x4)(0.f);

  int lrow = lane >> 3;                       // row-within-8 for staging
  int csrc = (lane & 7) ^ lrow;               // inverse-swizzled source k-granule

  // stage chunk c (2 A-loads + 6 B-loads per wave)
  auto stage = [&](int c) {
    const unsigned short* Ag; const unsigned short* Bg; int ld, k0;
    if (c < 20) { Ag = means; Bg = wih; ld = DIM_MSG; k0 = c * 64; }
    else        { Ag = memb;  Bg = whh; ld = DIM_MEM; k0 = (c - 20) * 64; }
#pragma unroll
    for (int i = 0; i < 2; i++) {             // A: 8 rows per load
      int rbase = (wid * 2 + i) * 8;
      int grow = row0 + rbase + lrow; if (grow > N_NODES - 1) grow = N_NODES - 1;
      const unsigned short* src = Ag + (size_t)grow * ld + k0 + csrc * 8;
      __builtin_amdgcn_global_load_lds(
          (const __attribute__((address_space(1))) void*)src,
          (__attribute__((address_space(3))) void*)&Al[rbase * 64],
          16, 0, 0);
    }
#pragma unroll
    for (int i = 0; i < 6; i++) {             // B: 8 gate-cols per load
      int gbase = (wid * 6 + i) * 8;
      int gcol = gbase + lrow;                // 0..191
      int st = gcol >> 6, col = gcol & 63;
      const unsigned short* src = Bg + (size_t)(st * 512 + c0 + col) * ld + k0 + csrc * 8;
      __builtin_amdgcn_global_load_lds(
          (const __attribute__((address_space(1))) void*)src,
          (__attribute__((address_space(3))) void*)&Bl[gbase * 64],
          16, 0, 0);
    }
  };

  // compute current chunk; PH=0: strips {0,1,2}; PH=1: strips {0,1,3}
  auto compute = [&](auto PH) {
    constexpr int ph = decltype(PH)::v;
    int g = lane >> 4, r = lane & 15;
#pragma unroll
    for (int t = 0; t < 2; t++) {
      int c16 = t * 4 + g;
      bf16x8 a[4], b[3];
#pragma unroll
      for (int f = 0; f < 4; f++) {
        int row = f * 16 + r;
        a[f] = *(const bf16x8*)&Al[(row * 8 + (c16 ^ (r & 7))) * 8];
      }
#pragma unroll
      for (int st = 0; st < 3; st++) {
        int gcol = st * 64 + wc * 16 + r;
        b[st] = *(const bf16x8*)&Bl[(gcol * 8 + (c16 ^ (r & 7))) * 8];
      }
#pragma unroll
      for (int f = 0; f < 4; f++)
#pragma unroll
        for (int st = 0; st < 3; st++) {
          constexpr int sm[2][3] = {{0, 1, 2}, {0, 1, 3}};
          acc[f][sm[ph][st]] = __builtin_amdgcn_mfma_f32_16x16x32_bf16(
              a[f], b[st], acc[f][sm[ph][st]], 0, 0, 0);
        }
    }
  };

  for (int c = 0; c < 20; ++c) {              // phase 1: r+=, z+=, i_n
    stage(c);
    __syncthreads();
    compute(ic<0>{});
    __syncthreads();
  }
  for (int c = 20; c < 28; ++c) {             // phase 2: r+=, z+=, h_n
    stage(c);
    __syncthreads();
    compute(ic<1>{});
    __syncthreads();
  }

  // ---- GRU epilogue ----
  int cc = c0 + wc * 16 + (lane & 15);
  float br = b_ih[cc] + b_hh[cc];
  float bz = b_ih[512 + cc] + b_hh[512 + cc];
  float bin = b_ih[1024 + cc], bhn = b_hh[1024 + cc];
  int g = lane >> 4;
#pragma unroll
  for (int f = 0; f < 4; f++) {
    int rbase = row0 + f * 16 + g * 4;
#pragma unroll
    for (int rr = 0; rr < 4; rr++) {
      int row = rbase + rr;
      if (row < N_NODES) {
        float rg = 1.f / (1.f + __expf(-(acc[f][0][rr] + br)));
        float zg = 1.f / (1.f + __expf(-(acc[f][1][rr] + bz)));
        float cd = tanhf(acc[f][2][rr] + bin + rg * (acc[f][3][rr] + bhn));
        float h = memory[(size_t)row * DIM_MEM + cc];
        float o = (counts[row] > 0) ? (1.f - zg) * cd + zg * h : h;
        out[(size_t)row * DIM_MEM + cc] = o;
      }
    }
  }
}

// ---------------- launch ----------------
extern "C" void kernel_launch(void* const* d_in, const int* in_sizes, int n_in,
                              void* d_out, int out_size, void* d_ws, size_t ws_size,
                              hipStream_t stream) {
  const float* msg  = (const float*)d_in[0];
  const int*   seg  = (const int*)d_in[1];
  const float* mem  = (const float*)d_in[2];
  const float* W_ih = (const float*)d_in[3];
  const float* W_hh = (const float*)d_in[4];
  const float* b_ih = (const float*)d_in[5];
  const float* b_hh = (const float*)d_in[6];
  float* out = (float*)d_out;

  char* ws = (char*)d_ws;
  unsigned short* means = (unsigned short*)(ws);                     // 128,000,000 B
  unsigned short* memb  = (unsigned short*)(ws + 128000000LL);       //  51,200,000 B
  unsigned short* wihb  = (unsigned short*)(ws + 179200000LL);       //   3,932,160 B
  unsigned short* whhb  = (unsigned short*)(ws + 183132160LL);       //   1,572,864 B
  int* counts           = (int*)(ws + 184705024LL);                  //     200,000 B

  k_segmean<<<N_NODES, 64, 0, stream>>>(msg, seg, means, counts);
  k_cvt<<<(N_NODES * DIM_MEM / 4 + 255) / 256, 256, 0, stream>>>(mem, memb, N_NODES * DIM_MEM / 4);
  k_cvt<<<(3 * DIM_MEM * DIM_MSG / 4 + 255) / 256, 256, 0, stream>>>(W_ih, wihb, 3 * DIM_MEM * DIM_MSG / 4);
  k_cvt<<<(3 * DIM_MEM * DIM_MEM / 4 + 255) / 256, 256, 0, stream>>>(W_hh, whhb, 3 * DIM_MEM * DIM_MEM / 4);

  dim3 grid(8, (N_NODES + 63) / 64, 1);   // blockIdx.x = col-tile (L2/XCD-aligned)
  k_gru<<<grid, 256, 0, stream>>>(means, memb, wihb, whhb, b_ih, b_hh, mem, counts, out);
}